// Round 1
// baseline (574.325 us; speedup 1.0000x reference)
//
#include <hip/hip_runtime.h>

// Problem constants (from reference)
#define L_   12
#define B_   16
#define NH_  12
#define S_   128
#define H_   768
#define K_   16
#define NC_  2
#define ALPHA_ 0.1f
#define BETA_  0.1f

__device__ __forceinline__ float waveReduceSum(float v) {
#pragma unroll
    for (int off = 32; off > 0; off >>= 1)
        v += __shfl_down(v, off, 64);
    return v;
}

// One block (256 threads) per (l, b, k). Each thread owns H columns
// {tid, tid+256, tid+512}. Reads are fully coalesced (stride-1 within
// each 256-thread chunk of a 768-float row).
__global__ void __launch_bounds__(256)
hid_loss_kernel(const float* __restrict__ t_hid,
                const float* __restrict__ s_hid,
                const int* __restrict__ t_align,
                const int* __restrict__ s_align,
                const int* __restrict__ cs_len,
                float* __restrict__ acc) {
    int idx = blockIdx.x;
    int k = idx % K_;
    int b = (idx / K_) % B_;
    int l = idx / (K_ * B_);
    if (k >= cs_len[b]) return;  // uniform across block

    int ts = t_align[(b * K_ + k) * 2 + 0];
    int te = t_align[(b * K_ + k) * 2 + 1];
    int ss = s_align[(b * K_ + k) * 2 + 0];
    int se = s_align[(b * K_ + k) * 2 + 1];
    float inv_lt = 1.0f / (float)max(te - ts, 1);
    float inv_ls = 1.0f / (float)max(se - ss, 1);

    const float* tb = t_hid + (size_t)(l * B_ + b) * S_ * H_;
    const float* sb = s_hid + (size_t)(l * B_ + b) * S_ * H_;
    int tid = threadIdx.x;

    float st0 = 0.f, st1 = 0.f, st2 = 0.f;
    for (int s = ts; s < te; ++s) {
        const float* r = tb + (size_t)s * H_;
        st0 += r[tid];
        st1 += r[tid + 256];
        st2 += r[tid + 512];
    }
    float su0 = 0.f, su1 = 0.f, su2 = 0.f;
    for (int s = ss; s < se; ++s) {
        const float* r = sb + (size_t)s * H_;
        su0 += r[tid];
        su1 += r[tid + 256];
        su2 += r[tid + 512];
    }
    float d0 = st0 * inv_lt - su0 * inv_ls;
    float d1 = st1 * inv_lt - su1 * inv_ls;
    float d2 = st2 * inv_lt - su2 * inv_ls;
    float sq = d0 * d0 + d1 * d1 + d2 * d2;

    sq = waveReduceSum(sq);
    __shared__ float wsum[4];
    int wid = tid >> 6, lane = tid & 63;
    if (lane == 0) wsum[wid] = sq;
    __syncthreads();
    if (tid == 0)
        atomicAdd(acc, wsum[0] + wsum[1] + wsum[2] + wsum[3]);
}

// One block (128 threads) per (l, b, nh, k). Thread = key index s.
__global__ void __launch_bounds__(128)
att_loss_kernel(const float* __restrict__ t_att,
                const float* __restrict__ s_att,
                const int* __restrict__ t_align,
                const int* __restrict__ s_align,
                const int* __restrict__ cs_len,
                float* __restrict__ acc) {
    int idx = blockIdx.x;
    int k = idx % K_;
    int nh = (idx / K_) % NH_;
    int b = (idx / (K_ * NH_)) % B_;
    int l = idx / (K_ * NH_ * B_);
    if (k >= cs_len[b]) return;  // uniform across block

    int ts = t_align[(b * K_ + k) * 2 + 0];
    int te = t_align[(b * K_ + k) * 2 + 1];
    int ss = s_align[(b * K_ + k) * 2 + 0];
    int se = s_align[(b * K_ + k) * 2 + 1];
    float inv_lt = 1.0f / (float)max(te - ts, 1);
    float inv_ls = 1.0f / (float)max(se - ss, 1);

    const float* tb = t_att + (((size_t)(l * B_ + b) * NH_ + nh)) * S_ * S_;
    const float* sb = s_att + (((size_t)(l * B_ + b) * NH_ + nh)) * S_ * S_;
    int tid = threadIdx.x;  // key index in [0, S_)

    float at = 0.f;
    for (int q = ts; q < te; ++q) {
        float v = tb[(size_t)q * S_ + tid];
        at += (v <= -100.0f) ? 0.0f : v;
    }
    float as = 0.f;
    for (int q = ss; q < se; ++q) {
        float v = sb[(size_t)q * S_ + tid];
        as += (v <= -100.0f) ? 0.0f : v;
    }
    float d = at * inv_lt - as * inv_ls;
    float sq = d * d;

    sq = waveReduceSum(sq);
    __shared__ float wsum[2];
    int wid = tid >> 6, lane = tid & 63;
    if (lane == 0) wsum[wid] = sq;
    __syncthreads();
    if (tid == 0)
        atomicAdd(acc + 1, wsum[0] + wsum[1]);
}

// Single wave: n_spans, final scaling, cross-entropy.
__global__ void __launch_bounds__(64)
finalize_kernel(const float* __restrict__ acc,
                const float* __restrict__ voted,
                const int* __restrict__ target,
                const int* __restrict__ cs_len,
                float* __restrict__ out) {
    int lane = threadIdx.x;

    float ns = (lane < B_) ? (float)cs_len[lane] : 0.f;
    ns = waveReduceSum(ns);
    ns = __shfl(ns, 0, 64);

    float pl = 0.f;
    if (lane < B_) {
        float a = voted[lane * NC_ + 0];
        float b = voted[lane * NC_ + 1];
        float m = fmaxf(a, b);
        float lse = m + logf(expf(a - m) + expf(b - m));
        float lp = voted[lane * NC_ + target[lane]] - lse;
        pl = -lp;
    }
    pl = waveReduceSum(pl);

    if (lane == 0) {
        float hid = (ns > 0.f)
            ? ALPHA_ * acc[0] / fmaxf(ns * (float)L_ * (float)H_, 1.0f) : 0.f;
        float att = (ns > 0.f)
            ? BETA_ * acc[1] / fmaxf(ns * (float)L_ * (float)NH_ * (float)S_, 1.0f) : 0.f;
        out[0] = hid;
        out[1] = att;
        out[2] = pl / (float)B_;
    }
}

extern "C" void kernel_launch(void* const* d_in, const int* in_sizes, int n_in,
                              void* d_out, int out_size, void* d_ws, size_t ws_size,
                              hipStream_t stream) {
    const float* voted   = (const float*)d_in[0];
    const int*   target  = (const int*)d_in[1];
    const float* t_hid   = (const float*)d_in[2];
    const float* t_att   = (const float*)d_in[3];
    const float* s_hid   = (const float*)d_in[4];
    const float* s_att   = (const float*)d_in[5];
    const int*   t_align = (const int*)d_in[6];
    const int*   s_align = (const int*)d_in[7];
    const int*   cs_len  = (const int*)d_in[8];
    float* out = (float*)d_out;
    float* acc = (float*)d_ws;  // acc[0]=hid_sq, acc[1]=att_sq

    hipMemsetAsync(acc, 0, 2 * sizeof(float), stream);

    hid_loss_kernel<<<L_ * B_ * K_, 256, 0, stream>>>(
        t_hid, s_hid, t_align, s_align, cs_len, acc);

    att_loss_kernel<<<L_ * B_ * NH_ * K_, 128, 0, stream>>>(
        t_att, s_att, t_align, s_align, cs_len, acc);

    finalize_kernel<<<1, 64, 0, stream>>>(acc, voted, target, cs_len, out);
}

// Round 2
// 568.335 us; speedup vs baseline: 1.0105x; 1.0105x over previous
//
#include <hip/hip_runtime.h>

// Problem constants (from reference)
#define L_   12
#define B_   16
#define NH_  12
#define S_   128
#define H_   768
#define K_   16
#define NC_  2
#define ALPHA_ 0.1f
#define BETA_  0.1f

#define NB_HID (L_ * B_ * K_)        // 3072
#define NB_ATT (L_ * B_ * NH_ * K_)  // 36864

__device__ __forceinline__ float waveReduceSum(float v) {
#pragma unroll
    for (int off = 32; off > 0; off >>= 1)
        v += __shfl_down(v, off, 64);
    return v;
}

// Fused hid + att loss. 64-thread (1-wave) blocks.
//   bid <  NB_HID : hidden-state path, one block per (l,b,k)
//   bid >= NB_HID : attention path, one block per (l,b,nh,k)
// Spans are always <= 8 rows (len in [1,8], start <= S-9), so the row loop
// is fully unrolled with addresses clamped to the last span row (extra
// iterations re-read the same row -> L1 hit, no HBM cost) and the
// accumulation predicated. All 16 loads issue before any use.
__global__ void __launch_bounds__(64)
fused_loss_kernel(const float* __restrict__ t_hid,
                  const float* __restrict__ s_hid,
                  const float* __restrict__ t_att,
                  const float* __restrict__ s_att,
                  const int* __restrict__ t_align,
                  const int* __restrict__ s_align,
                  const int* __restrict__ cs_len,
                  float* __restrict__ acc) {
    int bid = blockIdx.x;
    int lane = threadIdx.x;

    if (bid < NB_HID) {
        // ---------------- hidden-state span-mean MSE ----------------
        int k = bid % K_;
        int b = (bid / K_) % B_;
        int l = bid / (K_ * B_);
        if (k >= cs_len[b]) return;  // block-uniform

        int2 tsp = ((const int2*)t_align)[b * K_ + k];
        int2 ssp = ((const int2*)s_align)[b * K_ + k];
        int ts = tsp.x, te = tsp.y, ss = ssp.x, se = ssp.y;
        float inv_lt = 1.0f / (float)max(te - ts, 1);
        float inv_ls = 1.0f / (float)max(se - ss, 1);

        const float4* tb = (const float4*)t_hid + (size_t)(l * B_ + b) * (S_ * H_ / 4);
        const float4* sb = (const float4*)s_hid + (size_t)(l * B_ + b) * (S_ * H_ / 4);

        float sq = 0.f;
#pragma unroll
        for (int c = 0; c < 3; ++c) {  // 3 x 64 lanes x float4 = 768 cols
            int col = lane + c * 64;
            float4 tv[8], sv[8];
#pragma unroll
            for (int r = 0; r < 8; ++r)
                tv[r] = tb[min(ts + r, te - 1) * (H_ / 4) + col];
#pragma unroll
            for (int r = 0; r < 8; ++r)
                sv[r] = sb[min(ss + r, se - 1) * (H_ / 4) + col];

            float4 st = make_float4(0.f, 0.f, 0.f, 0.f);
            float4 su = make_float4(0.f, 0.f, 0.f, 0.f);
#pragma unroll
            for (int r = 0; r < 8; ++r) {
                if (ts + r < te) {
                    st.x += tv[r].x; st.y += tv[r].y;
                    st.z += tv[r].z; st.w += tv[r].w;
                }
                if (ss + r < se) {
                    su.x += sv[r].x; su.y += sv[r].y;
                    su.z += sv[r].z; su.w += sv[r].w;
                }
            }
            float dx = st.x * inv_lt - su.x * inv_ls;
            float dy = st.y * inv_lt - su.y * inv_ls;
            float dz = st.z * inv_lt - su.z * inv_ls;
            float dw = st.w * inv_lt - su.w * inv_ls;
            sq += dx * dx + dy * dy + dz * dz + dw * dw;
        }
        sq = waveReduceSum(sq);
        if (lane == 0) atomicAdd(acc + 0, sq);
    } else {
        // ---------------- attention span-mean MSE ----------------
        int idx = bid - NB_HID;
        int k = idx % K_;
        int nh = (idx / K_) % NH_;
        int b = (idx / (K_ * NH_)) % B_;
        int l = idx / (K_ * NH_ * B_);
        if (k >= cs_len[b]) return;  // block-uniform

        int2 tsp = ((const int2*)t_align)[b * K_ + k];
        int2 ssp = ((const int2*)s_align)[b * K_ + k];
        int ts = tsp.x, te = tsp.y, ss = ssp.x, se = ssp.y;
        float inv_lt = 1.0f / (float)max(te - ts, 1);
        float inv_ls = 1.0f / (float)max(se - ss, 1);

        const float2* tb = (const float2*)t_att
            + (size_t)((l * B_ + b) * NH_ + nh) * (S_ * S_ / 2);
        const float2* sb = (const float2*)s_att
            + (size_t)((l * B_ + b) * NH_ + nh) * (S_ * S_ / 2);

        // lane owns one float2 of the 128-wide key row
        float2 tv[8], sv[8];
#pragma unroll
        for (int r = 0; r < 8; ++r)
            tv[r] = tb[min(ts + r, te - 1) * (S_ / 2) + lane];
#pragma unroll
        for (int r = 0; r < 8; ++r)
            sv[r] = sb[min(ss + r, se - 1) * (S_ / 2) + lane];

        float atx = 0.f, aty = 0.f, asx = 0.f, asy = 0.f;
#pragma unroll
        for (int r = 0; r < 8; ++r) {
            if (ts + r < te) {
                atx += (tv[r].x > -100.0f) ? tv[r].x : 0.f;
                aty += (tv[r].y > -100.0f) ? tv[r].y : 0.f;
            }
            if (ss + r < se) {
                asx += (sv[r].x > -100.0f) ? sv[r].x : 0.f;
                asy += (sv[r].y > -100.0f) ? sv[r].y : 0.f;
            }
        }
        float dx = atx * inv_lt - asx * inv_ls;
        float dy = aty * inv_lt - asy * inv_ls;
        float sq = waveReduceSum(dx * dx + dy * dy);
        if (lane == 0) atomicAdd(acc + 1, sq);
    }
}

// Single wave: n_spans, final scaling, cross-entropy.
__global__ void __launch_bounds__(64)
finalize_kernel(const float* __restrict__ acc,
                const float* __restrict__ voted,
                const int* __restrict__ target,
                const int* __restrict__ cs_len,
                float* __restrict__ out) {
    int lane = threadIdx.x;

    float ns = (lane < B_) ? (float)cs_len[lane] : 0.f;
    ns = waveReduceSum(ns);
    ns = __shfl(ns, 0, 64);

    float pl = 0.f;
    if (lane < B_) {
        float a = voted[lane * NC_ + 0];
        float b = voted[lane * NC_ + 1];
        float m = fmaxf(a, b);
        float lse = m + logf(expf(a - m) + expf(b - m));
        float lp = voted[lane * NC_ + target[lane]] - lse;
        pl = -lp;
    }
    pl = waveReduceSum(pl);

    if (lane == 0) {
        float hid = (ns > 0.f)
            ? ALPHA_ * acc[0] / fmaxf(ns * (float)L_ * (float)H_, 1.0f) : 0.f;
        float att = (ns > 0.f)
            ? BETA_ * acc[1] / fmaxf(ns * (float)L_ * (float)NH_ * (float)S_, 1.0f) : 0.f;
        out[0] = hid;
        out[1] = att;
        out[2] = pl / (float)B_;
    }
}

extern "C" void kernel_launch(void* const* d_in, const int* in_sizes, int n_in,
                              void* d_out, int out_size, void* d_ws, size_t ws_size,
                              hipStream_t stream) {
    const float* voted   = (const float*)d_in[0];
    const int*   target  = (const int*)d_in[1];
    const float* t_hid   = (const float*)d_in[2];
    const float* t_att   = (const float*)d_in[3];
    const float* s_hid   = (const float*)d_in[4];
    const float* s_att   = (const float*)d_in[5];
    const int*   t_align = (const int*)d_in[6];
    const int*   s_align = (const int*)d_in[7];
    const int*   cs_len  = (const int*)d_in[8];
    float* out = (float*)d_out;
    float* acc = (float*)d_ws;  // acc[0]=hid_sq, acc[1]=att_sq

    hipMemsetAsync(acc, 0, 2 * sizeof(float), stream);

    fused_loss_kernel<<<NB_HID + NB_ATT, 64, 0, stream>>>(
        t_hid, s_hid, t_att, s_att, t_align, s_align, cs_len, acc);

    finalize_kernel<<<1, 64, 0, stream>>>(acc, voted, target, cs_len, out);
}